// Round 1
// baseline (875.562 us; speedup 1.0000x reference)
//
#include <hip/hip_runtime.h>
#include <hip/hip_bf16.h>

typedef __attribute__((ext_vector_type(8))) short bf16x8;
typedef __attribute__((ext_vector_type(4))) float f32x4;

#define MFMA(a,b,c) __builtin_amdgcn_mfma_f32_16x16x32_bf16((a),(b),(c),0,0,0)

// ---- workspace (bf16) element offsets ----
// w1T  [7][256][128]  @ 0        (229376)
// w2T  [7][128][256]  @ 229376   (229376)
// g1T  [256][256]     @ 458752   (65536)
// g2T  [256][256]     @ 524288   (65536)
// g3T  [256][256]     @ 589824   (65536)
// tgP  [384][64]      @ 655360   (24576)   tgP[r][i] = to_grid[r][i], zero-padded
// fgT  [64][384]      @ 679936   (24576)   fgT[i][r] = from_grid[r][i], zero-padded
#define WS_W1T 0
#define WS_W2T 229376
#define WS_G1T 458752
#define WS_TGP 655360
#define WS_FGT 679936
#define WS_TOTAL 704512

__device__ __forceinline__ ushort f2b(float f) {
  __hip_bfloat16 h = __float2bfloat16(f);
  ushort u; __builtin_memcpy(&u, &h, 2); return u;
}
__device__ __forceinline__ float silu_f(float x) { return x / (1.f + __expf(-x)); }
__device__ __forceinline__ bf16x8 ld8(const ushort* p) {
  return *reinterpret_cast<const bf16x8*>(p);
}

__global__ void prep_kernel(const float* __restrict__ w1, const float* __restrict__ w2,
                            const float* __restrict__ g1, const float* __restrict__ g2,
                            const float* __restrict__ g3, const float* __restrict__ tg,
                            const float* __restrict__ fg, ushort* __restrict__ o) {
  int idx = blockIdx.x * blockDim.x + threadIdx.x;
  if (idx >= WS_TOTAL) return;
  float v;
  if (idx < WS_W2T) {                        // w1T[l][h][c] = w1[l][c][h]
    int l = idx >> 15, rem = idx & 32767, h = rem >> 7, c = rem & 127;
    v = w1[(l << 15) + c * 256 + h];
  } else if (idx < WS_G1T) {                 // w2T[l][o][h] = w2[l][h][o]
    int j = idx - WS_W2T;
    int l = j >> 15, rem = j & 32767, oo = rem >> 8, h = rem & 255;
    v = w2[(l << 15) + h * 128 + oo];
  } else if (idx < WS_TGP) {                 // gT[n][k] = g[k][n]
    int j = idx - WS_G1T;
    int m = j >> 16, r = j & 65535, n2 = r >> 8, k = r & 255;
    const float* g = (m == 0) ? g1 : ((m == 1) ? g2 : g3);
    v = g[k * 256 + n2];
  } else if (idx < WS_FGT) {                 // tgP[r][i]
    int j = idx - WS_TGP, r = j >> 6, i2 = j & 63;
    v = (r < 324 && i2 < 49) ? tg[r * 49 + i2] : 0.f;
  } else {                                   // fgT[i][r]
    int j = idx - WS_FGT, i2 = j / 384, r = j % 384;
    v = (i2 < 49 && r < 324) ? fg[r * 49 + i2] : 0.f;
  }
  o[idx] = f2b(v);
}

// One block per node. 512 threads = 8 waves in a 2x4 (M x N) grid.
__global__ __launch_bounds__(512) void ffn_main(
    const float* __restrict__ nf, const float* __restrict__ b1,
    const float* __restrict__ b2, const float* __restrict__ wsg,
    const float* __restrict__ bs, const ushort* __restrict__ wbf,
    float* __restrict__ out)
{
  __shared__ __align__(16) ushort sm[54272];           // 108,544 B LDS
  ushort* s_xbT = sm;                                  // [256][72]  x^T (h-major, i-contig)
  ushort* s_G   = sm + 18432;                          // [64][264]  grid rows
  ushort* s_GT  = sm + 35328;                          // [256][72]  (alias: s_nf [52][136], s_xo [64][264])
  float*  s_gat = reinterpret_cast<float*>(sm + 53760); // [256]
  ushort* s_nf = s_GT;
  ushort* s_xo = s_GT;

  const int n    = blockIdx.x;
  const int tid  = threadIdx.x;
  const int lane = tid & 63;
  const int wv   = tid >> 6;    // 0..7
  const int wm   = wv >> 2;     // 0..1  (M half)
  const int wn   = wv & 3;      // 0..3  (N quarter)
  const int lr   = lane & 15;   // row/col within 16-tile
  const int lk   = lane >> 4;   // k-block 0..3

  const float* nfp = nf + (size_t)n * 6272;

  // ---------------- prologue: stage node_feats (bf16), zero xbT, gating ----------------
  for (int idx = tid; idx < 52 * 128; idx += 512) {
    int r = idx >> 7, c = idx & 127;
    s_nf[r * 136 + c] = f2b(r < 49 ? nfp[(r << 7) + c] : 0.f);
  }
  for (int idx = tid; idx < 18432; idx += 512) s_xbT[idx] = 0;
  if (tid < 256) {
    float a = bs[tid];
    for (int c = 0; c < 128; ++c) a = fmaf(nfp[c], wsg[(c << 8) + tid], a);
    s_gat[tid] = silu_f(a);
  }
  __syncthreads();

  // ---------------- SO3 linear 1: x[i,h] = nf[i,:] @ w1[deg(i)] (+b1 on i==0) ----------------
  {
    const ushort* w1T = wbf + WS_W1T;
    for (int l = 0; l < 7; ++l) {
      f32x4 a0 = {0.f,0.f,0.f,0.f}, a1 = {0.f,0.f,0.f,0.f};
      const int arow = l * l + lr;                    // <= 51, rows 49..51 zeroed
      const ushort* bb = w1T + (l << 15);
      #pragma unroll
      for (int ks = 0; ks < 4; ++ks) {
        bf16x8 af  = ld8(&s_nf[arow * 136 + ks * 32 + lk * 8]);
        bf16x8 bf0 = ld8(bb + ((wv * 32 + lr) << 7) + ks * 32 + lk * 8);
        bf16x8 bf1 = ld8(bb + ((wv * 32 + 16 + lr) << 7) + ks * 32 + lk * 8);
        a0 = MFMA(af, bf0, a0);
        a1 = MFMA(af, bf1, a1);
      }
      const int nv = 2 * l + 1;
      #pragma unroll
      for (int reg = 0; reg < 4; ++reg) {
        int il = lk * 4 + reg;
        if (il < nv) {
          int ig = l * l + il;
          int h0 = wv * 32 + lr, h1 = h0 + 16;
          s_xbT[h0 * 72 + ig] = f2b(a0[reg] + (ig == 0 ? b1[h0] : 0.f));
          s_xbT[h1 * 72 + ig] = f2b(a1[reg] + (ig == 0 ? b1[h1] : 0.f));
        }
      }
    }
  }
  __syncthreads();

  // ---------------- chunk loop over 6 x 64 grid rows ----------------
  f32x4 xo[2][4];
  #pragma unroll
  for (int mt = 0; mt < 2; ++mt)
    #pragma unroll
    for (int nt = 0; nt < 4; ++nt) xo[mt][nt] = (f32x4){0.f,0.f,0.f,0.f};

  const ushort* tgP = wbf + WS_TGP;
  const ushort* fgT = wbf + WS_FGT;

  for (int ch = 0; ch < 6; ++ch) {
    // (a) G0 = tg_chunk[64,64] @ x[64,256]   (K = padded 49->64)
    {
      f32x4 c[2][4];
      #pragma unroll
      for (int mt = 0; mt < 2; ++mt)
        #pragma unroll
        for (int nt = 0; nt < 4; ++nt) c[mt][nt] = (f32x4){0.f,0.f,0.f,0.f};
      #pragma unroll
      for (int ks = 0; ks < 2; ++ks) {
        bf16x8 af[2];
        #pragma unroll
        for (int mt = 0; mt < 2; ++mt)
          af[mt] = ld8(tgP + ((ch * 64 + wm * 32 + mt * 16 + lr) << 6) + ks * 32 + lk * 8);
        #pragma unroll
        for (int nt = 0; nt < 4; ++nt) {
          bf16x8 bfr = ld8(&s_xbT[(wn * 64 + nt * 16 + lr) * 72 + ks * 32 + lk * 8]);
          #pragma unroll
          for (int mt = 0; mt < 2; ++mt) c[mt][nt] = MFMA(af[mt], bfr, c[mt][nt]);
        }
      }
      #pragma unroll
      for (int mt = 0; mt < 2; ++mt)
        #pragma unroll
        for (int nt = 0; nt < 4; ++nt)
          #pragma unroll
          for (int reg = 0; reg < 4; ++reg) {
            int r = wm * 32 + mt * 16 + lk * 4 + reg;
            int h = wn * 64 + nt * 16 + lr;
            s_G[r * 264 + h] = f2b(c[mt][nt][reg]);
          }
    }
    __syncthreads();

    // (b,c,d) grid MLP: G = silu(G@g1); G = silu(G@g2); GT = (G@g3)^T
    #pragma unroll 1
    for (int pass = 0; pass < 3; ++pass) {
      const ushort* gT = wbf + WS_G1T + (pass << 16);
      f32x4 c[2][4];
      #pragma unroll
      for (int mt = 0; mt < 2; ++mt)
        #pragma unroll
        for (int nt = 0; nt < 4; ++nt) c[mt][nt] = (f32x4){0.f,0.f,0.f,0.f};
      #pragma unroll
      for (int ks = 0; ks < 8; ++ks) {
        bf16x8 af[2];
        #pragma unroll
        for (int mt = 0; mt < 2; ++mt)
          af[mt] = ld8(&s_G[(wm * 32 + mt * 16 + lr) * 264 + ks * 32 + lk * 8]);
        #pragma unroll
        for (int nt = 0; nt < 4; ++nt) {
          bf16x8 bfr = ld8(gT + ((wn * 64 + nt * 16 + lr) << 8) + ks * 32 + lk * 8);
          #pragma unroll
          for (int mt = 0; mt < 2; ++mt) c[mt][nt] = MFMA(af[mt], bfr, c[mt][nt]);
        }
      }
      __syncthreads();   // all reads of s_G done before overwrite
      if (pass < 2) {
        #pragma unroll
        for (int mt = 0; mt < 2; ++mt)
          #pragma unroll
          for (int nt = 0; nt < 4; ++nt)
            #pragma unroll
            for (int reg = 0; reg < 4; ++reg) {
              int r = wm * 32 + mt * 16 + lk * 4 + reg;
              int h = wn * 64 + nt * 16 + lr;
              s_G[r * 264 + h] = f2b(silu_f(c[mt][nt][reg]));
            }
      } else {
        #pragma unroll
        for (int mt = 0; mt < 2; ++mt)
          #pragma unroll
          for (int nt = 0; nt < 4; ++nt) {
            int r0 = wm * 32 + mt * 16 + lk * 4;
            int h  = wn * 64 + nt * 16 + lr;
            ushort4 pk = make_ushort4(f2b(c[mt][nt][0]), f2b(c[mt][nt][1]),
                                      f2b(c[mt][nt][2]), f2b(c[mt][nt][3]));
            *reinterpret_cast<ushort4*>(&s_GT[h * 72 + r0]) = pk;
          }
      }
      __syncthreads();
    }

    // (e) xo[49p64,256] += fg_chunk^T @ G3   (A = fgT global, B = s_GT)
    {
      #pragma unroll
      for (int ks = 0; ks < 2; ++ks) {
        bf16x8 af[2];
        #pragma unroll
        for (int mt = 0; mt < 2; ++mt)
          af[mt] = ld8(fgT + (wm * 32 + mt * 16 + lr) * 384 + ch * 64 + ks * 32 + lk * 8);
        #pragma unroll
        for (int nt = 0; nt < 4; ++nt) {
          bf16x8 bfr = ld8(&s_GT[(wn * 64 + nt * 16 + lr) * 72 + ks * 32 + lk * 8]);
          #pragma unroll
          for (int mt = 0; mt < 2; ++mt) xo[mt][nt] = MFMA(af[mt], bfr, xo[mt][nt]);
        }
      }
    }
    __syncthreads();
  }

  // ---------------- epilogue: xo -> LDS, gating row, SO3 linear 2 ----------------
  #pragma unroll
  for (int mt = 0; mt < 2; ++mt)
    #pragma unroll
    for (int nt = 0; nt < 4; ++nt)
      #pragma unroll
      for (int reg = 0; reg < 4; ++reg) {
        int i = wm * 32 + mt * 16 + lk * 4 + reg;
        int h = wn * 64 + nt * 16 + lr;
        s_xo[i * 264 + h] = f2b(xo[mt][nt][reg]);
      }
  __syncthreads();
  if (tid < 256) s_xo[tid] = f2b(s_gat[tid]);   // replace row 0 with gating
  __syncthreads();

  {
    const ushort* w2T = wbf + WS_W2T;
    float* outp = out + (size_t)n * 6272;
    for (int l = 0; l < 7; ++l) {
      f32x4 acc = {0.f,0.f,0.f,0.f};
      const ushort* bb = w2T + (l << 15);
      const int arow = l * l + lr;                 // <= 51; rows 49..63 are zeros
      #pragma unroll
      for (int ks = 0; ks < 8; ++ks) {
        bf16x8 af  = ld8(&s_xo[arow * 264 + ks * 32 + lk * 8]);
        bf16x8 bfr = ld8(bb + ((wv * 16 + lr) << 8) + ks * 32 + lk * 8);
        acc = MFMA(af, bfr, acc);
      }
      const int nv = 2 * l + 1;
      #pragma unroll
      for (int reg = 0; reg < 4; ++reg) {
        int il = lk * 4 + reg;
        if (il < nv) {
          int ig = l * l + il, o = wv * 16 + lr;
          outp[(ig << 7) + o] = acc[reg] + (ig == 0 ? b2[o] : 0.f);
        }
      }
    }
  }
}

extern "C" void kernel_launch(void* const* d_in, const int* in_sizes, int n_in,
                              void* d_out, int out_size, void* d_ws, size_t ws_size,
                              hipStream_t stream) {
  const float* nf  = (const float*)d_in[0];
  const float* w1  = (const float*)d_in[1];
  const float* b1  = (const float*)d_in[2];
  const float* w2  = (const float*)d_in[3];
  const float* b2  = (const float*)d_in[4];
  const float* wsg = (const float*)d_in[5];
  const float* bs  = (const float*)d_in[6];
  const float* g1  = (const float*)d_in[7];
  const float* g2  = (const float*)d_in[8];
  const float* g3  = (const float*)d_in[9];
  const float* tg  = (const float*)d_in[10];
  const float* fg  = (const float*)d_in[11];
  ushort* wbf = (ushort*)d_ws;
  float* out = (float*)d_out;

  prep_kernel<<<(WS_TOTAL + 255) / 256, 256, 0, stream>>>(w1, w2, g1, g2, g3, tg, fg, wbf);
  ffn_main<<<1024, 512, 0, stream>>>(nf, b1, b2, wsg, bs, wbf, out);
}

// Round 3
// 794.389 us; speedup vs baseline: 1.1022x; 1.1022x over previous
//
#include <hip/hip_runtime.h>
#include <hip/hip_bf16.h>

typedef __attribute__((ext_vector_type(8))) short bf16x8;
typedef __attribute__((ext_vector_type(4))) float f32x4;

#define MFMA(a,b,c) __builtin_amdgcn_mfma_f32_16x16x32_bf16((a),(b),(c),0,0,0)

// ---- workspace (bf16) element offsets ----
#define WS_W1T 0
#define WS_W2T 229376
#define WS_G1T 458752
#define WS_TGP 655360
#define WS_FGT 679936
#define WS_TOTAL 704512

__device__ __forceinline__ ushort f2b(float f) {
  __hip_bfloat16 h = __float2bfloat16(f);
  ushort u; __builtin_memcpy(&u, &h, 2); return u;
}
__device__ __forceinline__ float silu_f(float x) { return x / (1.f + __expf(-x)); }
__device__ __forceinline__ bf16x8 ld8(const ushort* p) {
  return *reinterpret_cast<const bf16x8*>(p);
}

__global__ void prep_kernel(const float* __restrict__ w1, const float* __restrict__ w2,
                            const float* __restrict__ g1, const float* __restrict__ g2,
                            const float* __restrict__ g3, const float* __restrict__ tg,
                            const float* __restrict__ fg, ushort* __restrict__ o) {
  int idx = blockIdx.x * blockDim.x + threadIdx.x;
  if (idx >= WS_TOTAL) return;
  float v;
  if (idx < WS_W2T) {                        // w1T[l][h][c] = w1[l][c][h]
    int l = idx >> 15, rem = idx & 32767, h = rem >> 7, c = rem & 127;
    v = w1[(l << 15) + c * 256 + h];
  } else if (idx < WS_G1T) {                 // w2T[l][o][h] = w2[l][h][o]
    int j = idx - WS_W2T;
    int l = j >> 15, rem = j & 32767, oo = rem >> 8, h = rem & 255;
    v = w2[(l << 15) + h * 128 + oo];
  } else if (idx < WS_TGP) {                 // gT[n][k] = g[k][n]
    int j = idx - WS_G1T;
    int m = j >> 16, r = j & 65535, n2 = r >> 8, k = r & 255;
    const float* g = (m == 0) ? g1 : ((m == 1) ? g2 : g3);
    v = g[k * 256 + n2];
  } else if (idx < WS_FGT) {                 // tgP[r][i]
    int j = idx - WS_TGP, r = j >> 6, i2 = j & 63;
    v = (r < 324 && i2 < 49) ? tg[r * 49 + i2] : 0.f;
  } else {                                   // fgT[i][r]
    int j = idx - WS_FGT, i2 = j / 384, r = j % 384;
    v = (i2 < 49 && r < 324) ? fg[r * 49 + i2] : 0.f;
  }
  o[idx] = f2b(v);
}

// One block per node. 512 threads = 8 waves (2 M x 4 N). 2 blocks/CU.
__global__ __launch_bounds__(512, 4) void ffn_main(
    const float* __restrict__ nf, const float* __restrict__ b1,
    const float* __restrict__ b2, const float* __restrict__ wsg,
    const float* __restrict__ bs, const ushort* __restrict__ wbf,
    float* __restrict__ out)
{
  // 71,680 B LDS -> 2 blocks/CU
  __shared__ __align__(16) ushort sm[35840];
  ushort* s_G   = sm;                                   // [64][264]  grid rows (16896)
  ushort* s_GT  = sm + 16896;                           // [256][72]  (alias: xT tmp) (18432)
  float*  s_gat = reinterpret_cast<float*>(sm + 35328); // [256]
  ushort* s_nf  = s_G;                                  // [52][136]  (7072, fits in s_G)
  ushort* s_xbT = s_GT;                                 // SO3L1 output x^T [256][72]
  ushort* s_xo  = s_G;                                  // epilogue [64][264]

  const int n    = blockIdx.x;
  const int tid  = threadIdx.x;
  const int lane = tid & 63;
  const int wv   = tid >> 6;    // 0..7
  const int wm   = wv >> 2;     // 0..1  (M half)
  const int wn   = wv & 3;      // 0..3  (N quarter)
  const int lr   = lane & 15;   // row/col within 16-tile
  const int lk   = lane >> 4;   // k-block 0..3

  const float* nfp = nf + (size_t)n * 6272;

  // ---------------- prologue: zero xT area, stage node_feats (bf16), gating ----------------
  {
    uint4 z = {0,0,0,0};
    for (int idx = tid; idx < 2304; idx += 512)         // 18432 ushorts
      *reinterpret_cast<uint4*>(&s_xbT[idx * 8]) = z;
    for (int idx = tid; idx < 52 * 32; idx += 512) {
      int r = idx >> 5, c4 = (idx & 31) << 2;
      float4 v = (r < 49) ? *reinterpret_cast<const float4*>(nfp + (r << 7) + c4)
                          : make_float4(0.f, 0.f, 0.f, 0.f);
      ushort4 pk = make_ushort4(f2b(v.x), f2b(v.y), f2b(v.z), f2b(v.w));
      *reinterpret_cast<ushort4*>(&s_nf[r * 136 + c4]) = pk;
    }
    if (tid < 256) {
      float a = bs[tid];
      #pragma unroll 4
      for (int c = 0; c < 128; ++c) a = fmaf(nfp[c], wsg[(c << 8) + tid], a);
      s_gat[tid] = silu_f(a);
    }
  }
  __syncthreads();

  // ---------------- SO3 linear 1: x^T[h][i] ----------------
  {
    const ushort* w1T = wbf + WS_W1T;
    #pragma unroll 1
    for (int l = 0; l < 7; ++l) {
      f32x4 a0 = {0.f,0.f,0.f,0.f}, a1 = {0.f,0.f,0.f,0.f};
      const int arow = l * l + lr;                    // <= 51, rows 49..51 zeroed
      const ushort* bb = w1T + (l << 15);
      #pragma unroll
      for (int ks = 0; ks < 4; ++ks) {
        bf16x8 af  = ld8(&s_nf[arow * 136 + ks * 32 + lk * 8]);
        bf16x8 bf0 = ld8(bb + ((wv * 32 + lr) << 7) + ks * 32 + lk * 8);
        bf16x8 bf1 = ld8(bb + ((wv * 32 + 16 + lr) << 7) + ks * 32 + lk * 8);
        a0 = MFMA(af, bf0, a0);
        a1 = MFMA(af, bf1, a1);
      }
      const int nv = 2 * l + 1;
      #pragma unroll
      for (int reg = 0; reg < 4; ++reg) {
        int il = lk * 4 + reg;
        if (il < nv) {
          int ig = l * l + il;
          int h0 = wv * 32 + lr, h1 = h0 + 16;
          s_xbT[h0 * 72 + ig] = f2b(a0[reg] + (ig == 0 ? b1[h0] : 0.f));
          s_xbT[h1 * 72 + ig] = f2b(a1[reg] + (ig == 0 ? b1[h1] : 0.f));
        }
      }
    }
  }
  __syncthreads();

  // ---------------- hoist to_grid B fragments (x^T slices) into registers ----------------
  bf16x8 xbf[4][2];
  #pragma unroll
  for (int nt = 0; nt < 4; ++nt)
    #pragma unroll
    for (int ks = 0; ks < 2; ++ks)
      xbf[nt][ks] = ld8(&s_xbT[(wn * 64 + nt * 16 + lr) * 72 + ks * 32 + lk * 8]);

  // ---------------- chunk loop over 6 x 64 grid rows ----------------
  f32x4 xo[2][4];
  #pragma unroll
  for (int mt = 0; mt < 2; ++mt)
    #pragma unroll
    for (int nt = 0; nt < 4; ++nt) xo[mt][nt] = (f32x4){0.f,0.f,0.f,0.f};

  const ushort* tgP = wbf + WS_TGP;
  const ushort* fgT = wbf + WS_FGT;

  #pragma unroll 1
  for (int ch = 0; ch < 6; ++ch) {
    // (a) G = tg_chunk[64,64p] @ x[64p,256]   (A global, B regs -> no LDS reads)
    {
      f32x4 c[2][4];
      #pragma unroll
      for (int mt = 0; mt < 2; ++mt)
        #pragma unroll
        for (int nt = 0; nt < 4; ++nt) c[mt][nt] = (f32x4){0.f,0.f,0.f,0.f};
      __builtin_amdgcn_s_setprio(1);
      #pragma unroll
      for (int ks = 0; ks < 2; ++ks) {
        bf16x8 af[2];
        #pragma unroll
        for (int mt = 0; mt < 2; ++mt)
          af[mt] = ld8(tgP + ((ch * 64 + wm * 32 + mt * 16 + lr) << 6) + ks * 32 + lk * 8);
        #pragma unroll
        for (int nt = 0; nt < 4; ++nt)
          #pragma unroll
          for (int mt = 0; mt < 2; ++mt) c[mt][nt] = MFMA(af[mt], xbf[nt][ks], c[mt][nt]);
      }
      __builtin_amdgcn_s_setprio(0);
      #pragma unroll
      for (int mt = 0; mt < 2; ++mt)
        #pragma unroll
        for (int nt = 0; nt < 4; ++nt)
          #pragma unroll
          for (int reg = 0; reg < 4; ++reg) {
            int r = wm * 32 + mt * 16 + lk * 4 + reg;
            int h = wn * 64 + nt * 16 + lr;
            s_G[r * 264 + h] = f2b(c[mt][nt][reg]);
          }
    }
    __syncthreads();

    // (b,c,d) grid MLP: G = silu(G@g1); G = silu(G@g2); GT = (G@g3)^T
    #pragma unroll 1
    for (int pass = 0; pass < 3; ++pass) {
      const ushort* gT = wbf + WS_G1T + (pass << 16);
      f32x4 c[2][4];
      #pragma unroll
      for (int mt = 0; mt < 2; ++mt)
        #pragma unroll
        for (int nt = 0; nt < 4; ++nt) c[mt][nt] = (f32x4){0.f,0.f,0.f,0.f};
      __builtin_amdgcn_s_setprio(1);
      #pragma unroll
      for (int ks = 0; ks < 8; ++ks) {
        bf16x8 af[2];
        #pragma unroll
        for (int mt = 0; mt < 2; ++mt)
          af[mt] = ld8(&s_G[(wm * 32 + mt * 16 + lr) * 264 + ks * 32 + lk * 8]);
        #pragma unroll
        for (int nt = 0; nt < 4; ++nt) {
          bf16x8 bfr = ld8(gT + ((wn * 64 + nt * 16 + lr) << 8) + ks * 32 + lk * 8);
          #pragma unroll
          for (int mt = 0; mt < 2; ++mt) c[mt][nt] = MFMA(af[mt], bfr, c[mt][nt]);
        }
      }
      __builtin_amdgcn_s_setprio(0);
      __syncthreads();   // all reads of s_G done before overwrite
      if (pass < 2) {
        #pragma unroll
        for (int mt = 0; mt < 2; ++mt)
          #pragma unroll
          for (int nt = 0; nt < 4; ++nt)
            #pragma unroll
            for (int reg = 0; reg < 4; ++reg) {
              int r = wm * 32 + mt * 16 + lk * 4 + reg;
              int h = wn * 64 + nt * 16 + lr;
              s_G[r * 264 + h] = f2b(silu_f(c[mt][nt][reg]));
            }
      } else {
        #pragma unroll
        for (int mt = 0; mt < 2; ++mt)
          #pragma unroll
          for (int nt = 0; nt < 4; ++nt) {
            int r0 = wm * 32 + mt * 16 + lk * 4;
            int h  = wn * 64 + nt * 16 + lr;
            ushort4 pk = make_ushort4(f2b(c[mt][nt][0]), f2b(c[mt][nt][1]),
                                      f2b(c[mt][nt][2]), f2b(c[mt][nt][3]));
            *reinterpret_cast<ushort4*>(&s_GT[h * 72 + r0]) = pk;
          }
      }
      __syncthreads();
    }

    // (e) xo[49p64,256] += fg_chunk^T @ G3   (A global, B = s_GT) -- no trailing barrier
    {
      __builtin_amdgcn_s_setprio(1);
      #pragma unroll
      for (int ks = 0; ks < 2; ++ks) {
        bf16x8 af[2];
        #pragma unroll
        for (int mt = 0; mt < 2; ++mt)
          af[mt] = ld8(fgT + (wm * 32 + mt * 16 + lr) * 384 + ch * 64 + ks * 32 + lk * 8);
        #pragma unroll
        for (int nt = 0; nt < 4; ++nt) {
          bf16x8 bfr = ld8(&s_GT[(wn * 64 + nt * 16 + lr) * 72 + ks * 32 + lk * 8]);
          #pragma unroll
          for (int mt = 0; mt < 2; ++mt) xo[mt][nt] = MFMA(af[mt], bfr, xo[mt][nt]);
        }
      }
      __builtin_amdgcn_s_setprio(0);
    }
    // next to_grid writes s_G (last read at pass3, already barriered); pass3's next
    // s_GT write is separated from these reads by >=4 barriers. No barrier needed here.
  }

  // ---------------- epilogue: xo -> LDS, gating row, SO3 linear 2 ----------------
  #pragma unroll
  for (int mt = 0; mt < 2; ++mt)
    #pragma unroll
    for (int nt = 0; nt < 4; ++nt)
      #pragma unroll
      for (int reg = 0; reg < 4; ++reg) {
        int i = wm * 32 + mt * 16 + lk * 4 + reg;
        int h = wn * 64 + nt * 16 + lr;
        s_xo[i * 264 + h] = f2b(xo[mt][nt][reg]);
      }
  __syncthreads();
  if (tid < 256) s_xo[tid] = f2b(s_gat[tid]);   // replace row 0 with gating
  __syncthreads();

  {
    const ushort* w2T = wbf + WS_W2T;
    float* outp = out + (size_t)n * 6272;
    #pragma unroll 1
    for (int l = 0; l < 7; ++l) {
      f32x4 acc = {0.f,0.f,0.f,0.f};
      const ushort* bb = w2T + (l << 15);
      const int arow = l * l + lr;                 // <= 51; rows 49..63 are zeros
      #pragma unroll
      for (int ks = 0; ks < 8; ++ks) {
        bf16x8 af  = ld8(&s_xo[arow * 264 + ks * 32 + lk * 8]);
        bf16x8 bfr = ld8(bb + ((wv * 16 + lr) << 8) + ks * 32 + lk * 8);
        acc = MFMA(af, bfr, acc);
      }
      const int nv = 2 * l + 1;
      #pragma unroll
      for (int reg = 0; reg < 4; ++reg) {
        int il = lk * 4 + reg;
        if (il < nv) {
          int ig = l * l + il, o = wv * 16 + lr;
          outp[(ig << 7) + o] = acc[reg] + (ig == 0 ? b2[o] : 0.f);
        }
      }
    }
  }
}

extern "C" void kernel_launch(void* const* d_in, const int* in_sizes, int n_in,
                              void* d_out, int out_size, void* d_ws, size_t ws_size,
                              hipStream_t stream) {
  const float* nf  = (const float*)d_in[0];
  const float* w1  = (const float*)d_in[1];
  const float* b1  = (const float*)d_in[2];
  const float* w2  = (const float*)d_in[3];
  const float* b2  = (const float*)d_in[4];
  const float* wsg = (const float*)d_in[5];
  const float* bs  = (const float*)d_in[6];
  const float* g1  = (const float*)d_in[7];
  const float* g2  = (const float*)d_in[8];
  const float* g3  = (const float*)d_in[9];
  const float* tg  = (const float*)d_in[10];
  const float* fg  = (const float*)d_in[11];
  ushort* wbf = (ushort*)d_ws;
  float* out = (float*)d_out;

  prep_kernel<<<(WS_TOTAL + 255) / 256, 256, 0, stream>>>(w1, w2, g1, g2, g3, tg, fg, wbf);
  ffn_main<<<1024, 512, 0, stream>>>(nf, b1, b2, wsg, bs, wbf, out);
}

// Round 4
// 639.164 us; speedup vs baseline: 1.3699x; 1.2429x over previous
//
#include <hip/hip_runtime.h>
#include <hip/hip_bf16.h>

typedef __attribute__((ext_vector_type(8))) short bf16x8;
typedef __attribute__((ext_vector_type(4))) float f32x4;

#define MFMA(a,b,c) __builtin_amdgcn_mfma_f32_16x16x32_bf16((a),(b),(c),0,0,0)

// ---- workspace (bf16) element offsets ----
#define WS_W1T 0
#define WS_W2T 229376
#define WS_G1T 458752
#define WS_TGP 655360
#define WS_FGT 679936
#define WS_TOTAL 704512

__device__ __forceinline__ ushort f2b(float f) {
  __hip_bfloat16 h = __float2bfloat16(f);
  ushort u; __builtin_memcpy(&u, &h, 2); return u;
}
__device__ __forceinline__ float silu_f(float x) { return x / (1.f + __expf(-x)); }
__device__ __forceinline__ bf16x8 ld8(const ushort* p) {
  return *reinterpret_cast<const bf16x8*>(p);
}

__global__ void prep_kernel(const float* __restrict__ w1, const float* __restrict__ w2,
                            const float* __restrict__ g1, const float* __restrict__ g2,
                            const float* __restrict__ g3, const float* __restrict__ tg,
                            const float* __restrict__ fg, ushort* __restrict__ o) {
  int idx = blockIdx.x * blockDim.x + threadIdx.x;
  if (idx >= WS_TOTAL) return;
  float v;
  if (idx < WS_W2T) {                        // w1T[l][h][c] = w1[l][c][h]
    int l = idx >> 15, rem = idx & 32767, h = rem >> 7, c = rem & 127;
    v = w1[(l << 15) + c * 256 + h];
  } else if (idx < WS_G1T) {                 // w2T[l][o][h] = w2[l][h][o]
    int j = idx - WS_W2T;
    int l = j >> 15, rem = j & 32767, oo = rem >> 8, h = rem & 255;
    v = w2[(l << 15) + h * 128 + oo];
  } else if (idx < WS_TGP) {                 // gT[n][k] = g[k][n]
    int j = idx - WS_G1T;
    int m = j >> 16, r = j & 65535, n2 = r >> 8, k = r & 255;
    const float* g = (m == 0) ? g1 : ((m == 1) ? g2 : g3);
    v = g[k * 256 + n2];
  } else if (idx < WS_FGT) {                 // tgP[r][i]
    int j = idx - WS_TGP, r = j >> 6, i2 = j & 63;
    v = (r < 324 && i2 < 49) ? tg[r * 49 + i2] : 0.f;
  } else {                                   // fgT[i][r]
    int j = idx - WS_FGT, i2 = j / 384, r = j % 384;
    v = (i2 < 49 && r < 324) ? fg[r * 49 + i2] : 0.f;
  }
  o[idx] = f2b(v);
}

// One block per node. 8 waves, N-split 8-way: wave wv owns cols [wv*32, wv*32+32).
// g1 B-fragments persistent in registers; g2/g3 streamed from L2; A from LDS.
__global__ __launch_bounds__(512, 2) void ffn_main(
    const float* __restrict__ nf, const float* __restrict__ b1,
    const float* __restrict__ b2, const float* __restrict__ wsg,
    const float* __restrict__ bs, const ushort* __restrict__ wbf,
    float* __restrict__ out)
{
  // 71,680 B LDS
  __shared__ __align__(16) ushort sm[35840];
  ushort* s_G   = sm;                                   // [64][264] grid rows (16896 ush)
  ushort* s_xbT = sm + 16896;                           // [256][72] x^T; later s_GT
  float*  s_gat = reinterpret_cast<float*>(sm + 35328); // [256]
  ushort* s_GT  = s_xbT;
  ushort* s_nf  = s_G;                                  // [52][136] prologue alias
  ushort* s_xo  = s_G;                                  // epilogue alias [64][264]

  const int tid  = threadIdx.x;
  const int lane = tid & 63;
  const int wv   = tid >> 6;    // 0..7 (N slice)
  const int lr   = lane & 15;
  const int lk   = lane >> 4;   // 0..3

  const float* nfp = nf + (size_t)blockIdx.x * 6272;

  // ---------------- prologue: zero x^T area, stage node_feats (bf16), gating ----------------
  {
    uint4 z = {0,0,0,0};
    for (int idx = tid; idx < 2304; idx += 512)         // 18432 ushorts
      *reinterpret_cast<uint4*>(&s_xbT[idx * 8]) = z;
    for (int idx = tid; idx < 52 * 32; idx += 512) {
      int r = idx >> 5, c4 = (idx & 31) << 2;
      float4 v = (r < 49) ? *reinterpret_cast<const float4*>(nfp + (r << 7) + c4)
                          : make_float4(0.f, 0.f, 0.f, 0.f);
      ushort4 pk = make_ushort4(f2b(v.x), f2b(v.y), f2b(v.z), f2b(v.w));
      *reinterpret_cast<ushort4*>(&s_nf[r * 136 + c4]) = pk;
    }
    if (tid < 256) {
      float a = bs[tid];
      #pragma unroll 4
      for (int c = 0; c < 128; ++c) a = fmaf(nfp[c], wsg[(c << 8) + tid], a);
      s_gat[tid] = silu_f(a);
    }
  }
  __syncthreads();

  // ---------------- SO3 linear 1: x^T[h][i] into s_xbT ----------------
  {
    const ushort* w1T = wbf + WS_W1T;
    #pragma unroll 1
    for (int l = 0; l < 7; ++l) {
      f32x4 a0 = {0.f,0.f,0.f,0.f}, a1 = {0.f,0.f,0.f,0.f};
      const int arow = l * l + lr;                    // <= 51, rows 49..51 zeroed
      const ushort* bb = w1T + (l << 15);
      #pragma unroll
      for (int ks = 0; ks < 4; ++ks) {
        bf16x8 af  = ld8(&s_nf[arow * 136 + ks * 32 + lk * 8]);
        bf16x8 bf0 = ld8(bb + ((wv * 32 + lr) << 7) + ks * 32 + lk * 8);
        bf16x8 bf1 = ld8(bb + ((wv * 32 + 16 + lr) << 7) + ks * 32 + lk * 8);
        a0 = MFMA(af, bf0, a0);
        a1 = MFMA(af, bf1, a1);
      }
      const int nv = 2 * l + 1;
      #pragma unroll
      for (int reg = 0; reg < 4; ++reg) {
        int il = lk * 4 + reg;
        if (il < nv) {
          int ig = l * l + il;
          int h0 = wv * 32 + lr, h1 = h0 + 16;
          s_xbT[h0 * 72 + ig] = f2b(a0[reg] + (ig == 0 ? b1[h0] : 0.f));
          s_xbT[h1 * 72 + ig] = f2b(a1[reg] + (ig == 0 ? b1[h1] : 0.f));
        }
      }
    }
  }
  __syncthreads();

  // ---------------- persistent register operands ----------------
  // to_grid B: x^T col-slice (16 VGPRs)
  bf16x8 xbf[2][2];
  #pragma unroll
  for (int nt = 0; nt < 2; ++nt)
    #pragma unroll
    for (int ks = 0; ks < 2; ++ks)
      xbf[nt][ks] = ld8(&s_xbT[(wv * 32 + nt * 16 + lr) * 72 + ks * 32 + lk * 8]);

  // g1 B-fragments, persistent (64 VGPRs), loaded once per block
  bf16x8 g1f[2][8];
  {
    const ushort* g1T = wbf + WS_G1T;
    #pragma unroll
    for (int nt = 0; nt < 2; ++nt)
      #pragma unroll
      for (int ks = 0; ks < 8; ++ks)
        g1f[nt][ks] = ld8(g1T + ((wv * 32 + nt * 16 + lr) << 8) + ks * 32 + lk * 8);
  }

  f32x4 xo[4][2];
  #pragma unroll
  for (int mt = 0; mt < 4; ++mt)
    #pragma unroll
    for (int nt = 0; nt < 2; ++nt) xo[mt][nt] = (f32x4){0.f,0.f,0.f,0.f};

  const ushort* tgP = wbf + WS_TGP;
  const ushort* fgT = wbf + WS_FGT;
  const ushort* g2T = wbf + WS_G1T + 65536;
  const ushort* g3T = wbf + WS_G1T + 131072;

  #pragma unroll 1
  for (int ch = 0; ch < 6; ++ch) {
    // ---- TG: G = tg_chunk[64,64p] @ x[64p,256]  (A global-L1, B regs) ----
    {
      f32x4 c[4][2];
      #pragma unroll
      for (int mt = 0; mt < 4; ++mt)
        #pragma unroll
        for (int nt = 0; nt < 2; ++nt) c[mt][nt] = (f32x4){0.f,0.f,0.f,0.f};
      #pragma unroll
      for (int ks = 0; ks < 2; ++ks) {
        bf16x8 atg[4];
        #pragma unroll
        for (int mt = 0; mt < 4; ++mt)
          atg[mt] = ld8(tgP + ((ch * 64 + mt * 16 + lr) << 6) + ks * 32 + lk * 8);
        #pragma unroll
        for (int mt = 0; mt < 4; ++mt)
          #pragma unroll
          for (int nt = 0; nt < 2; ++nt) c[mt][nt] = MFMA(atg[mt], xbf[nt][ks], c[mt][nt]);
      }
      #pragma unroll
      for (int mt = 0; mt < 4; ++mt)
        #pragma unroll
        for (int nt = 0; nt < 2; ++nt)
          #pragma unroll
          for (int reg = 0; reg < 4; ++reg)
            s_G[(mt * 16 + lk * 4 + reg) * 264 + wv * 32 + nt * 16 + lr] = f2b(c[mt][nt][reg]);
    }
    __syncthreads();

    // ---- G1: silu(G @ g1), B persistent in regs ----
    {
      f32x4 c[4][2];
      #pragma unroll
      for (int mt = 0; mt < 4; ++mt)
        #pragma unroll
        for (int nt = 0; nt < 2; ++nt) c[mt][nt] = (f32x4){0.f,0.f,0.f,0.f};
      #pragma unroll
      for (int ks = 0; ks < 8; ++ks) {
        bf16x8 af[4];
        #pragma unroll
        for (int mt = 0; mt < 4; ++mt)
          af[mt] = ld8(&s_G[(mt * 16 + lr) * 264 + ks * 32 + lk * 8]);
        #pragma unroll
        for (int mt = 0; mt < 4; ++mt)
          #pragma unroll
          for (int nt = 0; nt < 2; ++nt) c[mt][nt] = MFMA(af[mt], g1f[nt][ks], c[mt][nt]);
      }
      __syncthreads();   // all reads of s_G done before overwrite
      #pragma unroll
      for (int mt = 0; mt < 4; ++mt)
        #pragma unroll
        for (int nt = 0; nt < 2; ++nt)
          #pragma unroll
          for (int reg = 0; reg < 4; ++reg)
            s_G[(mt * 16 + lk * 4 + reg) * 264 + wv * 32 + nt * 16 + lr] = f2b(silu_f(c[mt][nt][reg]));
    }
    __syncthreads();

    // ---- G2: silu(G @ g2), B streamed from L2 ----
    {
      f32x4 c[4][2];
      #pragma unroll
      for (int mt = 0; mt < 4; ++mt)
        #pragma unroll
        for (int nt = 0; nt < 2; ++nt) c[mt][nt] = (f32x4){0.f,0.f,0.f,0.f};
      #pragma unroll
      for (int ks = 0; ks < 8; ++ks) {
        bf16x8 bstr[2];
        #pragma unroll
        for (int nt = 0; nt < 2; ++nt)
          bstr[nt] = ld8(g2T + ((wv * 32 + nt * 16 + lr) << 8) + ks * 32 + lk * 8);
        bf16x8 af[4];
        #pragma unroll
        for (int mt = 0; mt < 4; ++mt)
          af[mt] = ld8(&s_G[(mt * 16 + lr) * 264 + ks * 32 + lk * 8]);
        #pragma unroll
        for (int mt = 0; mt < 4; ++mt)
          #pragma unroll
          for (int nt = 0; nt < 2; ++nt) c[mt][nt] = MFMA(af[mt], bstr[nt], c[mt][nt]);
      }
      __syncthreads();
      #pragma unroll
      for (int mt = 0; mt < 4; ++mt)
        #pragma unroll
        for (int nt = 0; nt < 2; ++nt)
          #pragma unroll
          for (int reg = 0; reg < 4; ++reg)
            s_G[(mt * 16 + lk * 4 + reg) * 264 + wv * 32 + nt * 16 + lr] = f2b(silu_f(c[mt][nt][reg]));
    }
    __syncthreads();

    // ---- G3: G @ g3, B streamed; write transposed into s_GT ----
    {
      f32x4 c[4][2];
      #pragma unroll
      for (int mt = 0; mt < 4; ++mt)
        #pragma unroll
        for (int nt = 0; nt < 2; ++nt) c[mt][nt] = (f32x4){0.f,0.f,0.f,0.f};
      #pragma unroll
      for (int ks = 0; ks < 8; ++ks) {
        bf16x8 bstr[2];
        #pragma unroll
        for (int nt = 0; nt < 2; ++nt)
          bstr[nt] = ld8(g3T + ((wv * 32 + nt * 16 + lr) << 8) + ks * 32 + lk * 8);
        bf16x8 af[4];
        #pragma unroll
        for (int mt = 0; mt < 4; ++mt)
          af[mt] = ld8(&s_G[(mt * 16 + lr) * 264 + ks * 32 + lk * 8]);
        #pragma unroll
        for (int mt = 0; mt < 4; ++mt)
          #pragma unroll
          for (int nt = 0; nt < 2; ++nt) c[mt][nt] = MFMA(af[mt], bstr[nt], c[mt][nt]);
      }
      __syncthreads();   // s_G reads done (next TG overwrites s_G)
      #pragma unroll
      for (int mt = 0; mt < 4; ++mt)
        #pragma unroll
        for (int nt = 0; nt < 2; ++nt) {
          int h = wv * 32 + nt * 16 + lr;
          ushort4 pk = make_ushort4(f2b(c[mt][nt][0]), f2b(c[mt][nt][1]),
                                    f2b(c[mt][nt][2]), f2b(c[mt][nt][3]));
          *reinterpret_cast<ushort4*>(&s_GT[h * 72 + mt * 16 + lk * 4]) = pk;
        }
    }
    __syncthreads();

    // ---- FG: xo += fg_chunk^T @ G3   (A global-L1, B = s_GT). No trailing barrier. ----
    {
      #pragma unroll
      for (int ks = 0; ks < 2; ++ks) {
        bf16x8 afg[4];
        #pragma unroll
        for (int mt = 0; mt < 4; ++mt)
          afg[mt] = ld8(fgT + (mt * 16 + lr) * 384 + ch * 64 + ks * 32 + lk * 8);
        bf16x8 bfr[2];
        #pragma unroll
        for (int nt = 0; nt < 2; ++nt)
          bfr[nt] = ld8(&s_GT[(wv * 32 + nt * 16 + lr) * 72 + ks * 32 + lk * 8]);
        #pragma unroll
        for (int mt = 0; mt < 4; ++mt)
          #pragma unroll
          for (int nt = 0; nt < 2; ++nt) xo[mt][nt] = MFMA(afg[mt], bfr[nt], xo[mt][nt]);
      }
    }
    // s_GT reads here vs next G3 writes: separated by >=5 barriers. s_G writes (next TG)
    // vs this G3's s_G reads: separated by G3's two barriers.
  }

  // ---------------- epilogue: xo -> LDS, gating row, SO3 linear 2 ----------------
  #pragma unroll
  for (int mt = 0; mt < 4; ++mt)
    #pragma unroll
    for (int nt = 0; nt < 2; ++nt)
      #pragma unroll
      for (int reg = 0; reg < 4; ++reg)
        s_xo[(mt * 16 + lk * 4 + reg) * 264 + wv * 32 + nt * 16 + lr] = f2b(xo[mt][nt][reg]);
  __syncthreads();
  if (tid < 256) s_xo[tid] = f2b(s_gat[tid]);   // replace row 0 with gating
  __syncthreads();

  {
    const ushort* w2T = wbf + WS_W2T;
    float* outp = out + (size_t)blockIdx.x * 6272;
    #pragma unroll 1
    for (int l = 0; l < 7; ++l) {
      f32x4 acc = {0.f,0.f,0.f,0.f};
      const ushort* bb = w2T + (l << 15);
      const int arow = l * l + lr;                 // <= 51; rows 49..63 are zeros
      #pragma unroll
      for (int ks = 0; ks < 8; ++ks) {
        bf16x8 af  = ld8(&s_xo[arow * 264 + ks * 32 + lk * 8]);
        bf16x8 bfr = ld8(bb + ((wv * 16 + lr) << 8) + ks * 32 + lk * 8);
        acc = MFMA(af, bfr, acc);
      }
      const int nv = 2 * l + 1;
      #pragma unroll
      for (int reg = 0; reg < 4; ++reg) {
        int il = lk * 4 + reg;
        if (il < nv) {
          int ig = l * l + il, o = wv * 16 + lr;
          outp[(ig << 7) + o] = acc[reg] + (ig == 0 ? b2[o] : 0.f);
        }
      }
    }
  }
}

extern "C" void kernel_launch(void* const* d_in, const int* in_sizes, int n_in,
                              void* d_out, int out_size, void* d_ws, size_t ws_size,
                              hipStream_t stream) {
  const float* nf  = (const float*)d_in[0];
  const float* w1  = (const float*)d_in[1];
  const float* b1  = (const float*)d_in[2];
  const float* w2  = (const float*)d_in[3];
  const float* b2  = (const float*)d_in[4];
  const float* wsg = (const float*)d_in[5];
  const float* bs  = (const float*)d_in[6];
  const float* g1  = (const float*)d_in[7];
  const float* g2  = (const float*)d_in[8];
  const float* g3  = (const float*)d_in[9];
  const float* tg  = (const float*)d_in[10];
  const float* fg  = (const float*)d_in[11];
  ushort* wbf = (ushort*)d_ws;
  float* out = (float*)d_out;

  prep_kernel<<<(WS_TOTAL + 255) / 256, 256, 0, stream>>>(w1, w2, g1, g2, g3, tg, fg, wbf);
  ffn_main<<<1024, 512, 0, stream>>>(nf, b1, b2, wsg, bs, wbf, out);
}

// Round 5
// 638.874 us; speedup vs baseline: 1.3705x; 1.0005x over previous
//
#include <hip/hip_runtime.h>
#include <hip/hip_bf16.h>

typedef __attribute__((ext_vector_type(8))) short bf16x8;
typedef __attribute__((ext_vector_type(4))) float f32x4;

#define MFMA(a,b,c) __builtin_amdgcn_mfma_f32_16x16x32_bf16((a),(b),(c),0,0,0)

// ---- workspace (bf16) element offsets ----
#define WS_W1T 0
#define WS_W2T 229376
#define WS_G1T 458752
#define WS_TGP 655360
#define WS_FGT 679936
#define WS_TOTAL 704512

__device__ __forceinline__ ushort f2b(float f) {
  __hip_bfloat16 h = __float2bfloat16(f);
  ushort u; __builtin_memcpy(&u, &h, 2); return u;
}
__device__ __forceinline__ float silu_f(float x) { return x / (1.f + __expf(-x)); }
__device__ __forceinline__ bf16x8 ld8(const ushort* p) {
  return *reinterpret_cast<const bf16x8*>(p);
}

__global__ void prep_kernel(const float* __restrict__ w1, const float* __restrict__ w2,
                            const float* __restrict__ g1, const float* __restrict__ g2,
                            const float* __restrict__ g3, const float* __restrict__ tg,
                            const float* __restrict__ fg, ushort* __restrict__ o) {
  int idx = blockIdx.x * blockDim.x + threadIdx.x;
  if (idx >= WS_TOTAL) return;
  float v;
  if (idx < WS_W2T) {                        // w1T[l][h][c] = w1[l][c][h]
    int l = idx >> 15, rem = idx & 32767, h = rem >> 7, c = rem & 127;
    v = w1[(l << 15) + c * 256 + h];
  } else if (idx < WS_G1T) {                 // w2T[l][o][h] = w2[l][h][o]
    int j = idx - WS_W2T;
    int l = j >> 15, rem = j & 32767, oo = rem >> 8, h = rem & 255;
    v = w2[(l << 15) + h * 128 + oo];
  } else if (idx < WS_TGP) {                 // gT[n][k] = g[k][n]
    int j = idx - WS_G1T;
    int m = j >> 16, r = j & 65535, n2 = r >> 8, k = r & 255;
    const float* g = (m == 0) ? g1 : ((m == 1) ? g2 : g3);
    v = g[k * 256 + n2];
  } else if (idx < WS_FGT) {                 // tgP[r][i]
    int j = idx - WS_TGP, r = j >> 6, i2 = j & 63;
    v = (r < 324 && i2 < 49) ? tg[r * 49 + i2] : 0.f;
  } else {                                   // fgT[i][r]
    int j = idx - WS_FGT, i2 = j / 384, r = j % 384;
    v = (i2 < 49 && r < 324) ? fg[r * 49 + i2] : 0.f;
  }
  o[idx] = f2b(v);
}

// One block per node. 8 waves, N-split 8-way: wave wv owns cols [wv*32, wv*32+32).
// g1 B-fragments persistent in registers; g2/g3 streamed from L2; A from LDS.
// launch_bounds(512,1): NO register cap -> no scratch spills (round-4 lesson:
// (512,2) forced VGPR=128 and spilled ~128MB/dispatch to scratch).
__global__ __launch_bounds__(512, 1) void ffn_main(
    const float* __restrict__ nf, const float* __restrict__ b1,
    const float* __restrict__ b2, const float* __restrict__ wsg,
    const float* __restrict__ bs, const ushort* __restrict__ wbf,
    float* __restrict__ out)
{
  // 71,680 B LDS
  __shared__ __align__(16) ushort sm[35840];
  ushort* s_G   = sm;                                   // [64][264] grid rows (16896 ush)
  ushort* s_xbT = sm + 16896;                           // [256][72] x^T; later s_GT
  float*  s_gat = reinterpret_cast<float*>(sm + 35328); // [256]
  ushort* s_GT  = s_xbT;
  ushort* s_nf  = s_G;                                  // [52][136] prologue alias
  ushort* s_xo  = s_G;                                  // epilogue alias [64][264]

  const int tid  = threadIdx.x;
  const int lane = tid & 63;
  const int wv   = tid >> 6;    // 0..7 (N slice)
  const int lr   = lane & 15;
  const int lk   = lane >> 4;   // 0..3

  const float* nfp = nf + (size_t)blockIdx.x * 6272;

  // ---------------- prologue: zero x^T area, stage node_feats (bf16), gating ----------------
  {
    uint4 z = {0,0,0,0};
    for (int idx = tid; idx < 2304; idx += 512)         // 18432 ushorts
      *reinterpret_cast<uint4*>(&s_xbT[idx * 8]) = z;
    for (int idx = tid; idx < 52 * 32; idx += 512) {
      int r = idx >> 5, c4 = (idx & 31) << 2;
      float4 v = (r < 49) ? *reinterpret_cast<const float4*>(nfp + (r << 7) + c4)
                          : make_float4(0.f, 0.f, 0.f, 0.f);
      ushort4 pk = make_ushort4(f2b(v.x), f2b(v.y), f2b(v.z), f2b(v.w));
      *reinterpret_cast<ushort4*>(&s_nf[r * 136 + c4]) = pk;
    }
    if (tid < 256) {
      float a = bs[tid];
      #pragma unroll 4
      for (int c = 0; c < 128; ++c) a = fmaf(nfp[c], wsg[(c << 8) + tid], a);
      s_gat[tid] = silu_f(a);
    }
  }
  __syncthreads();

  // ---------------- SO3 linear 1: x^T[h][i] into s_xbT ----------------
  {
    const ushort* w1T = wbf + WS_W1T;
    #pragma unroll 1
    for (int l = 0; l < 7; ++l) {
      f32x4 a0 = {0.f,0.f,0.f,0.f}, a1 = {0.f,0.f,0.f,0.f};
      const int arow = l * l + lr;                    // <= 51, rows 49..51 zeroed
      const ushort* bb = w1T + (l << 15);
      #pragma unroll
      for (int ks = 0; ks < 4; ++ks) {
        bf16x8 af  = ld8(&s_nf[arow * 136 + ks * 32 + lk * 8]);
        bf16x8 bf0 = ld8(bb + ((wv * 32 + lr) << 7) + ks * 32 + lk * 8);
        bf16x8 bf1 = ld8(bb + ((wv * 32 + 16 + lr) << 7) + ks * 32 + lk * 8);
        a0 = MFMA(af, bf0, a0);
        a1 = MFMA(af, bf1, a1);
      }
      const int nv = 2 * l + 1;
      #pragma unroll
      for (int reg = 0; reg < 4; ++reg) {
        int il = lk * 4 + reg;
        if (il < nv) {
          int ig = l * l + il;
          int h0 = wv * 32 + lr, h1 = h0 + 16;
          s_xbT[h0 * 72 + ig] = f2b(a0[reg] + (ig == 0 ? b1[h0] : 0.f));
          s_xbT[h1 * 72 + ig] = f2b(a1[reg] + (ig == 0 ? b1[h1] : 0.f));
        }
      }
    }
  }
  __syncthreads();

  // ---------------- persistent register operands ----------------
  // to_grid B: x^T col-slice (16 VGPRs)
  bf16x8 xbf[2][2];
  #pragma unroll
  for (int nt = 0; nt < 2; ++nt)
    #pragma unroll
    for (int ks = 0; ks < 2; ++ks)
      xbf[nt][ks] = ld8(&s_xbT[(wv * 32 + nt * 16 + lr) * 72 + ks * 32 + lk * 8]);

  // g1 B-fragments, persistent (64 VGPRs), loaded once per block
  bf16x8 g1f[2][8];
  {
    const ushort* g1T = wbf + WS_G1T;
    #pragma unroll
    for (int nt = 0; nt < 2; ++nt)
      #pragma unroll
      for (int ks = 0; ks < 8; ++ks)
        g1f[nt][ks] = ld8(g1T + ((wv * 32 + nt * 16 + lr) << 8) + ks * 32 + lk * 8);
  }

  f32x4 xo[4][2];
  #pragma unroll
  for (int mt = 0; mt < 4; ++mt)
    #pragma unroll
    for (int nt = 0; nt < 2; ++nt) xo[mt][nt] = (f32x4){0.f,0.f,0.f,0.f};

  const ushort* tgP = wbf + WS_TGP;
  const ushort* fgT = wbf + WS_FGT;
  const ushort* g2T = wbf + WS_G1T + 65536;
  const ushort* g3T = wbf + WS_G1T + 131072;

  #pragma unroll 1
  for (int ch = 0; ch < 6; ++ch) {
    // ---- TG: G = tg_chunk[64,64p] @ x[64p,256]  (A global-L1, B regs) ----
    {
      f32x4 c[4][2];
      #pragma unroll
      for (int mt = 0; mt < 4; ++mt)
        #pragma unroll
        for (int nt = 0; nt < 2; ++nt) c[mt][nt] = (f32x4){0.f,0.f,0.f,0.f};
      #pragma unroll
      for (int ks = 0; ks < 2; ++ks) {
        bf16x8 atg[4];
        #pragma unroll
        for (int mt = 0; mt < 4; ++mt)
          atg[mt] = ld8(tgP + ((ch * 64 + mt * 16 + lr) << 6) + ks * 32 + lk * 8);
        #pragma unroll
        for (int mt = 0; mt < 4; ++mt)
          #pragma unroll
          for (int nt = 0; nt < 2; ++nt) c[mt][nt] = MFMA(atg[mt], xbf[nt][ks], c[mt][nt]);
      }
      #pragma unroll
      for (int mt = 0; mt < 4; ++mt)
        #pragma unroll
        for (int nt = 0; nt < 2; ++nt)
          #pragma unroll
          for (int reg = 0; reg < 4; ++reg)
            s_G[(mt * 16 + lk * 4 + reg) * 264 + wv * 32 + nt * 16 + lr] = f2b(c[mt][nt][reg]);
    }
    __syncthreads();

    // ---- G1: silu(G @ g1), B persistent in regs ----
    {
      f32x4 c[4][2];
      #pragma unroll
      for (int mt = 0; mt < 4; ++mt)
        #pragma unroll
        for (int nt = 0; nt < 2; ++nt) c[mt][nt] = (f32x4){0.f,0.f,0.f,0.f};
      #pragma unroll
      for (int ks = 0; ks < 8; ++ks) {
        bf16x8 af[4];
        #pragma unroll
        for (int mt = 0; mt < 4; ++mt)
          af[mt] = ld8(&s_G[(mt * 16 + lr) * 264 + ks * 32 + lk * 8]);
        #pragma unroll
        for (int mt = 0; mt < 4; ++mt)
          #pragma unroll
          for (int nt = 0; nt < 2; ++nt) c[mt][nt] = MFMA(af[mt], g1f[nt][ks], c[mt][nt]);
      }
      __syncthreads();   // all reads of s_G done before overwrite
      #pragma unroll
      for (int mt = 0; mt < 4; ++mt)
        #pragma unroll
        for (int nt = 0; nt < 2; ++nt)
          #pragma unroll
          for (int reg = 0; reg < 4; ++reg)
            s_G[(mt * 16 + lk * 4 + reg) * 264 + wv * 32 + nt * 16 + lr] = f2b(silu_f(c[mt][nt][reg]));
    }
    __syncthreads();

    // ---- G2: silu(G @ g2), B streamed from L2 ----
    {
      f32x4 c[4][2];
      #pragma unroll
      for (int mt = 0; mt < 4; ++mt)
        #pragma unroll
        for (int nt = 0; nt < 2; ++nt) c[mt][nt] = (f32x4){0.f,0.f,0.f,0.f};
      #pragma unroll
      for (int ks = 0; ks < 8; ++ks) {
        bf16x8 bstr[2];
        #pragma unroll
        for (int nt = 0; nt < 2; ++nt)
          bstr[nt] = ld8(g2T + ((wv * 32 + nt * 16 + lr) << 8) + ks * 32 + lk * 8);
        bf16x8 af[4];
        #pragma unroll
        for (int mt = 0; mt < 4; ++mt)
          af[mt] = ld8(&s_G[(mt * 16 + lr) * 264 + ks * 32 + lk * 8]);
        #pragma unroll
        for (int mt = 0; mt < 4; ++mt)
          #pragma unroll
          for (int nt = 0; nt < 2; ++nt) c[mt][nt] = MFMA(af[mt], bstr[nt], c[mt][nt]);
      }
      __syncthreads();
      #pragma unroll
      for (int mt = 0; mt < 4; ++mt)
        #pragma unroll
        for (int nt = 0; nt < 2; ++nt)
          #pragma unroll
          for (int reg = 0; reg < 4; ++reg)
            s_G[(mt * 16 + lk * 4 + reg) * 264 + wv * 32 + nt * 16 + lr] = f2b(silu_f(c[mt][nt][reg]));
    }
    __syncthreads();

    // ---- G3: G @ g3, B streamed; write transposed into s_GT ----
    {
      f32x4 c[4][2];
      #pragma unroll
      for (int mt = 0; mt < 4; ++mt)
        #pragma unroll
        for (int nt = 0; nt < 2; ++nt) c[mt][nt] = (f32x4){0.f,0.f,0.f,0.f};
      #pragma unroll
      for (int ks = 0; ks < 8; ++ks) {
        bf16x8 bstr[2];
        #pragma unroll
        for (int nt = 0; nt < 2; ++nt)
          bstr[nt] = ld8(g3T + ((wv * 32 + nt * 16 + lr) << 8) + ks * 32 + lk * 8);
        bf16x8 af[4];
        #pragma unroll
        for (int mt = 0; mt < 4; ++mt)
          af[mt] = ld8(&s_G[(mt * 16 + lr) * 264 + ks * 32 + lk * 8]);
        #pragma unroll
        for (int mt = 0; mt < 4; ++mt)
          #pragma unroll
          for (int nt = 0; nt < 2; ++nt) c[mt][nt] = MFMA(af[mt], bstr[nt], c[mt][nt]);
      }
      __syncthreads();   // s_G reads done (next TG overwrites s_G)
      #pragma unroll
      for (int mt = 0; mt < 4; ++mt)
        #pragma unroll
        for (int nt = 0; nt < 2; ++nt) {
          int h = wv * 32 + nt * 16 + lr;
          ushort4 pk = make_ushort4(f2b(c[mt][nt][0]), f2b(c[mt][nt][1]),
                                    f2b(c[mt][nt][2]), f2b(c[mt][nt][3]));
          *reinterpret_cast<ushort4*>(&s_GT[h * 72 + mt * 16 + lk * 4]) = pk;
        }
    }
    __syncthreads();

    // ---- FG: xo += fg_chunk^T @ G3   (A global-L1, B = s_GT). No trailing barrier. ----
    {
      #pragma unroll
      for (int ks = 0; ks < 2; ++ks) {
        bf16x8 afg[4];
        #pragma unroll
        for (int mt = 0; mt < 4; ++mt)
          afg[mt] = ld8(fgT + (mt * 16 + lr) * 384 + ch * 64 + ks * 32 + lk * 8);
        bf16x8 bfr[2];
        #pragma unroll
        for (int nt = 0; nt < 2; ++nt)
          bfr[nt] = ld8(&s_GT[(wv * 32 + nt * 16 + lr) * 72 + ks * 32 + lk * 8]);
        #pragma unroll
        for (int mt = 0; mt < 4; ++mt)
          #pragma unroll
          for (int nt = 0; nt < 2; ++nt) xo[mt][nt] = MFMA(afg[mt], bfr[nt], xo[mt][nt]);
      }
    }
    // s_GT reads here vs next G3 writes: separated by >=5 barriers. s_G writes (next TG)
    // vs this G3's s_G reads: separated by G3's two barriers.
  }

  // ---------------- epilogue: xo -> LDS, gating row, SO3 linear 2 ----------------
  #pragma unroll
  for (int mt = 0; mt < 4; ++mt)
    #pragma unroll
    for (int nt = 0; nt < 2; ++nt)
      #pragma unroll
      for (int reg = 0; reg < 4; ++reg)
        s_xo[(mt * 16 + lk * 4 + reg) * 264 + wv * 32 + nt * 16 + lr] = f2b(xo[mt][nt][reg]);
  __syncthreads();
  if (tid < 256) s_xo[tid] = f2b(s_gat[tid]);   // replace row 0 with gating
  __syncthreads();

  {
    const ushort* w2T = wbf + WS_W2T;
    float* outp = out + (size_t)blockIdx.x * 6272;
    #pragma unroll 1
    for (int l = 0; l < 7; ++l) {
      f32x4 acc = {0.f,0.f,0.f,0.f};
      const ushort* bb = w2T + (l << 15);
      const int arow = l * l + lr;                 // <= 51; rows 49..63 are zeros
      #pragma unroll
      for (int ks = 0; ks < 8; ++ks) {
        bf16x8 af  = ld8(&s_xo[arow * 264 + ks * 32 + lk * 8]);
        bf16x8 bfr = ld8(bb + ((wv * 16 + lr) << 8) + ks * 32 + lk * 8);
        acc = MFMA(af, bfr, acc);
      }
      const int nv = 2 * l + 1;
      #pragma unroll
      for (int reg = 0; reg < 4; ++reg) {
        int il = lk * 4 + reg;
        if (il < nv) {
          int ig = l * l + il, o = wv * 16 + lr;
          outp[(ig << 7) + o] = acc[reg] + (ig == 0 ? b2[o] : 0.f);
        }
      }
    }
  }
}

extern "C" void kernel_launch(void* const* d_in, const int* in_sizes, int n_in,
                              void* d_out, int out_size, void* d_ws, size_t ws_size,
                              hipStream_t stream) {
  const float* nf  = (const float*)d_in[0];
  const float* w1  = (const float*)d_in[1];
  const float* b1  = (const float*)d_in[2];
  const float* w2  = (const float*)d_in[3];
  const float* b2  = (const float*)d_in[4];
  const float* wsg = (const float*)d_in[5];
  const float* bs  = (const float*)d_in[6];
  const float* g1  = (const float*)d_in[7];
  const float* g2  = (const float*)d_in[8];
  const float* g3  = (const float*)d_in[9];
  const float* tg  = (const float*)d_in[10];
  const float* fg  = (const float*)d_in[11];
  ushort* wbf = (ushort*)d_ws;
  float* out = (float*)d_out;

  prep_kernel<<<(WS_TOTAL + 255) / 256, 256, 0, stream>>>(w1, w2, g1, g2, g3, tg, fg, wbf);
  ffn_main<<<1024, 512, 0, stream>>>(nf, b1, b2, wsg, bs, wbf, out);
}

// Round 7
// 631.878 us; speedup vs baseline: 1.3857x; 1.0111x over previous
//
#include <hip/hip_runtime.h>
#include <hip/hip_bf16.h>

typedef __attribute__((ext_vector_type(8))) short bf16x8;
typedef __attribute__((ext_vector_type(4))) float f32x4;

#define MFMA(a,b,c) __builtin_amdgcn_mfma_f32_16x16x32_bf16((a),(b),(c),0,0,0)

// ---- workspace (bf16) element offsets ----
#define WS_W1T 0
#define WS_W2T 229376
#define WS_G1T 458752
#define WS_TGP 655360
#define WS_FGT 679936
#define WS_TOTAL 704512

__device__ __forceinline__ ushort f2b(float f) {
  __hip_bfloat16 h = __float2bfloat16(f);
  ushort u; __builtin_memcpy(&u, &h, 2); return u;
}
__device__ __forceinline__ float silu_f(float x) { return x / (1.f + __expf(-x)); }
__device__ __forceinline__ bf16x8 ld8(const ushort* p) {
  return *reinterpret_cast<const bf16x8*>(p);
}

__global__ void prep_kernel(const float* __restrict__ w1, const float* __restrict__ w2,
                            const float* __restrict__ g1, const float* __restrict__ g2,
                            const float* __restrict__ g3, const float* __restrict__ tg,
                            const float* __restrict__ fg, ushort* __restrict__ o) {
  int idx = blockIdx.x * blockDim.x + threadIdx.x;
  if (idx >= WS_TOTAL) return;
  float v;
  if (idx < WS_W2T) {                        // w1T[l][h][c] = w1[l][c][h]
    int l = idx >> 15, rem = idx & 32767, h = rem >> 7, c = rem & 127;
    v = w1[(l << 15) + c * 256 + h];
  } else if (idx < WS_G1T) {                 // w2T[l][o][h] = w2[l][h][o]
    int j = idx - WS_W2T;
    int l = j >> 15, rem = j & 32767, oo = rem >> 8, h = rem & 255;
    v = w2[(l << 15) + h * 128 + oo];
  } else if (idx < WS_TGP) {                 // gT[n][k] = g[k][n]
    int j = idx - WS_G1T;
    int m = j >> 16, r = j & 65535, n2 = r >> 8, k = r & 255;
    const float* g = (m == 0) ? g1 : ((m == 1) ? g2 : g3);
    v = g[k * 256 + n2];
  } else if (idx < WS_FGT) {                 // tgP[r][i]
    int j = idx - WS_TGP, r = j >> 6, i2 = j & 63;
    v = (r < 324 && i2 < 49) ? tg[r * 49 + i2] : 0.f;
  } else {                                   // fgT[i][r]
    int j = idx - WS_FGT, i2 = j / 384, r = j % 384;
    v = (i2 < 49 && r < 324) ? fg[r * 49 + i2] : 0.f;
  }
  o[idx] = f2b(v);
}

// One block per node. 8 waves, N-split 8-way: wave wv owns cols [wv*32, wv*32+32).
// ALL g-matrices streamed from L2 (round-5 lesson: persistent g1 regs blew the
// 256-total unified reg cap for 8-wave blocks and spilled ~128MB/dispatch).
__global__ __launch_bounds__(512, 1) void ffn_main(
    const float* __restrict__ nf, const float* __restrict__ b1,
    const float* __restrict__ b2, const float* __restrict__ wsg,
    const float* __restrict__ bs, const ushort* __restrict__ wbf,
    float* __restrict__ out)
{
  // 71,680 B LDS
  __shared__ __align__(16) ushort sm[35840];
  ushort* s_G   = sm;                                   // [64][264] grid rows (16896 ush)
  ushort* s_xbT = sm + 16896;                           // [256][72] x^T; later s_GT
  float*  s_gat = reinterpret_cast<float*>(sm + 35328); // [256]
  ushort* s_GT  = s_xbT;
  ushort* s_nf  = s_G;                                  // [52][136] prologue alias
  ushort* s_xo  = s_G;                                  // epilogue alias [64][264]

  const int tid  = threadIdx.x;
  const int lane = tid & 63;
  const int wv   = tid >> 6;    // 0..7 (N slice)
  const int lr   = lane & 15;
  const int lk   = lane >> 4;   // 0..3

  const float* nfp = nf + (size_t)blockIdx.x * 6272;

  // ---------------- prologue: zero x^T area, stage node_feats (bf16), gating ----------------
  {
    uint4 z = {0,0,0,0};
    for (int idx = tid; idx < 2304; idx += 512)         // 18432 ushorts
      *reinterpret_cast<uint4*>(&s_xbT[idx * 8]) = z;
    for (int idx = tid; idx < 52 * 32; idx += 512) {
      int r = idx >> 5, c4 = (idx & 31) << 2;
      float4 v = (r < 49) ? *reinterpret_cast<const float4*>(nfp + (r << 7) + c4)
                          : make_float4(0.f, 0.f, 0.f, 0.f);
      ushort4 pk = make_ushort4(f2b(v.x), f2b(v.y), f2b(v.z), f2b(v.w));
      *reinterpret_cast<ushort4*>(&s_nf[r * 136 + c4]) = pk;
    }
    if (tid < 256) {
      float a = bs[tid];
      #pragma unroll 4
      for (int c = 0; c < 128; ++c) a = fmaf(nfp[c], wsg[(c << 8) + tid], a);
      s_gat[tid] = silu_f(a);
    }
  }
  __syncthreads();

  // ---------------- SO3 linear 1: x^T[h][i] into s_xbT ----------------
  {
    const ushort* w1T = wbf + WS_W1T;
    #pragma unroll 1
    for (int l = 0; l < 7; ++l) {
      f32x4 a0 = {0.f,0.f,0.f,0.f}, a1 = {0.f,0.f,0.f,0.f};
      const int arow = l * l + lr;                    // <= 51, rows 49..51 zeroed
      const ushort* bb = w1T + (l << 15);
      #pragma unroll
      for (int ks = 0; ks < 4; ++ks) {
        bf16x8 af  = ld8(&s_nf[arow * 136 + ks * 32 + lk * 8]);
        bf16x8 bf0 = ld8(bb + ((wv * 32 + lr) << 7) + ks * 32 + lk * 8);
        bf16x8 bf1 = ld8(bb + ((wv * 32 + 16 + lr) << 7) + ks * 32 + lk * 8);
        a0 = MFMA(af, bf0, a0);
        a1 = MFMA(af, bf1, a1);
      }
      const int nv = 2 * l + 1;
      #pragma unroll
      for (int reg = 0; reg < 4; ++reg) {
        int il = lk * 4 + reg;
        if (il < nv) {
          int ig = l * l + il;
          int h0 = wv * 32 + lr, h1 = h0 + 16;
          s_xbT[h0 * 72 + ig] = f2b(a0[reg] + (ig == 0 ? b1[h0] : 0.f));
          s_xbT[h1 * 72 + ig] = f2b(a1[reg] + (ig == 0 ? b1[h1] : 0.f));
        }
      }
    }
  }
  __syncthreads();

  // ---------------- persistent register operands ----------------
  // to_grid B: x^T col-slice (16 VGPRs). Must be in regs: s_xbT is overwritten
  // by s_GT each chunk.
  bf16x8 xbf[2][2];
  #pragma unroll
  for (int nt = 0; nt < 2; ++nt)
    #pragma unroll
    for (int ks = 0; ks < 2; ++ks)
      xbf[nt][ks] = ld8(&s_xbT[(wv * 32 + nt * 16 + lr) * 72 + ks * 32 + lk * 8]);

  f32x4 xo[4][2];
  #pragma unroll
  for (int mt = 0; mt < 4; ++mt)
    #pragma unroll
    for (int nt = 0; nt < 2; ++nt) xo[mt][nt] = (f32x4){0.f,0.f,0.f,0.f};

  const ushort* tgP = wbf + WS_TGP;
  const ushort* fgT = wbf + WS_FGT;

  #pragma unroll 1
  for (int ch = 0; ch < 6; ++ch) {
    // ---- TG: G = tg_chunk[64,64p] @ x[64p,256]  (A global-L1, B regs) ----
    {
      f32x4 c[4][2];
      #pragma unroll
      for (int mt = 0; mt < 4; ++mt)
        #pragma unroll
        for (int nt = 0; nt < 2; ++nt) c[mt][nt] = (f32x4){0.f,0.f,0.f,0.f};
      #pragma unroll
      for (int ks = 0; ks < 2; ++ks) {
        bf16x8 atg[4];
        #pragma unroll
        for (int mt = 0; mt < 4; ++mt)
          atg[mt] = ld8(tgP + ((ch * 64 + mt * 16 + lr) << 6) + ks * 32 + lk * 8);
        #pragma unroll
        for (int mt = 0; mt < 4; ++mt)
          #pragma unroll
          for (int nt = 0; nt < 2; ++nt) c[mt][nt] = MFMA(atg[mt], xbf[nt][ks], c[mt][nt]);
      }
      #pragma unroll
      for (int mt = 0; mt < 4; ++mt)
        #pragma unroll
        for (int nt = 0; nt < 2; ++nt)
          #pragma unroll
          for (int reg = 0; reg < 4; ++reg)
            s_G[(mt * 16 + lk * 4 + reg) * 264 + wv * 32 + nt * 16 + lr] = f2b(c[mt][nt][reg]);
    }
    __syncthreads();

    // ---- G-MLP passes 0,1: silu(G @ g), B streamed from L2, in-place s_G ----
    #pragma unroll 1
    for (int pass = 0; pass < 2; ++pass) {
      const ushort* gT = wbf + WS_G1T + (pass << 16);
      f32x4 c[4][2];
      #pragma unroll
      for (int mt = 0; mt < 4; ++mt)
        #pragma unroll
        for (int nt = 0; nt < 2; ++nt) c[mt][nt] = (f32x4){0.f,0.f,0.f,0.f};
      #pragma unroll
      for (int ks = 0; ks < 8; ++ks) {
        bf16x8 bstr[2];
        #pragma unroll
        for (int nt = 0; nt < 2; ++nt)
          bstr[nt] = ld8(gT + ((wv * 32 + nt * 16 + lr) << 8) + ks * 32 + lk * 8);
        bf16x8 af[4];
        #pragma unroll
        for (int mt = 0; mt < 4; ++mt)
          af[mt] = ld8(&s_G[(mt * 16 + lr) * 264 + ks * 32 + lk * 8]);
        #pragma unroll
        for (int mt = 0; mt < 4; ++mt)
          #pragma unroll
          for (int nt = 0; nt < 2; ++nt) c[mt][nt] = MFMA(af[mt], bstr[nt], c[mt][nt]);
      }
      __syncthreads();   // all reads of s_G done before overwrite
      #pragma unroll
      for (int mt = 0; mt < 4; ++mt)
        #pragma unroll
        for (int nt = 0; nt < 2; ++nt)
          #pragma unroll
          for (int reg = 0; reg < 4; ++reg)
            s_G[(mt * 16 + lk * 4 + reg) * 264 + wv * 32 + nt * 16 + lr] = f2b(silu_f(c[mt][nt][reg]));
      __syncthreads();
    }

    // ---- G3: G @ g3, B streamed; write transposed into s_GT ----
    {
      const ushort* g3T = wbf + WS_G1T + 131072;
      f32x4 c[4][2];
      #pragma unroll
      for (int mt = 0; mt < 4; ++mt)
        #pragma unroll
        for (int nt = 0; nt < 2; ++nt) c[mt][nt] = (f32x4){0.f,0.f,0.f,0.f};
      #pragma unroll
      for (int ks = 0; ks < 8; ++ks) {
        bf16x8 bstr[2];
        #pragma unroll
        for (int nt = 0; nt < 2; ++nt)
          bstr[nt] = ld8(g3T + ((wv * 32 + nt * 16 + lr) << 8) + ks * 32 + lk * 8);
        bf16x8 af[4];
        #pragma unroll
        for (int mt = 0; mt < 4; ++mt)
          af[mt] = ld8(&s_G[(mt * 16 + lr) * 264 + ks * 32 + lk * 8]);
        #pragma unroll
        for (int mt = 0; mt < 4; ++mt)
          #pragma unroll
          for (int nt = 0; nt < 2; ++nt) c[mt][nt] = MFMA(af[mt], bstr[nt], c[mt][nt]);
      }
      __syncthreads();   // s_G reads done (next TG overwrites s_G)
      #pragma unroll
      for (int mt = 0; mt < 4; ++mt)
        #pragma unroll
        for (int nt = 0; nt < 2; ++nt) {
          int h = wv * 32 + nt * 16 + lr;
          ushort4 pk = make_ushort4(f2b(c[mt][nt][0]), f2b(c[mt][nt][1]),
                                    f2b(c[mt][nt][2]), f2b(c[mt][nt][3]));
          *reinterpret_cast<ushort4*>(&s_GT[h * 72 + mt * 16 + lk * 4]) = pk;
        }
    }
    __syncthreads();

    // ---- FG: xo += fg_chunk^T @ G3   (A global-L1, B = s_GT). No trailing barrier. ----
    {
      #pragma unroll
      for (int ks = 0; ks < 2; ++ks) {
        bf16x8 afg[4];
        #pragma unroll
        for (int mt = 0; mt < 4; ++mt)
          afg[mt] = ld8(fgT + (mt * 16 + lr) * 384 + ch * 64 + ks * 32 + lk * 8);
        bf16x8 bfr[2];
        #pragma unroll
        for (int nt = 0; nt < 2; ++nt)
          bfr[nt] = ld8(&s_GT[(wv * 32 + nt * 16 + lr) * 72 + ks * 32 + lk * 8]);
        #pragma unroll
        for (int mt = 0; mt < 4; ++mt)
          #pragma unroll
          for (int nt = 0; nt < 2; ++nt) xo[mt][nt] = MFMA(afg[mt], bfr[nt], xo[mt][nt]);
      }
    }
    // s_GT reads here vs next G3 writes: separated by >=5 barriers. s_G writes (next TG)
    // vs this G3's s_G reads: separated by G3's two barriers.
  }

  // ---------------- epilogue: xo -> LDS, gating row, SO3 linear 2 ----------------
  #pragma unroll
  for (int mt = 0; mt < 4; ++mt)
    #pragma unroll
    for (int nt = 0; nt < 2; ++nt)
      #pragma unroll
      for (int reg = 0; reg < 4; ++reg)
        s_xo[(mt * 16 + lk * 4 + reg) * 264 + wv * 32 + nt * 16 + lr] = f2b(xo[mt][nt][reg]);
  __syncthreads();
  if (tid < 256) s_xo[tid] = f2b(s_gat[tid]);   // replace row 0 with gating
  __syncthreads();

  {
    const ushort* w2T = wbf + WS_W2T;
    float* outp = out + (size_t)blockIdx.x * 6272;
    #pragma unroll 1
    for (int l = 0; l < 7; ++l) {
      f32x4 acc = {0.f,0.f,0.f,0.f};
      const ushort* bb = w2T + (l << 15);
      const int arow = l * l + lr;                 // <= 51; rows 49..63 are zeros
      #pragma unroll
      for (int ks = 0; ks < 8; ++ks) {
        bf16x8 af  = ld8(&s_xo[arow * 264 + ks * 32 + lk * 8]);
        bf16x8 bfr = ld8(bb + ((wv * 16 + lr) << 8) + ks * 32 + lk * 8);
        acc = MFMA(af, bfr, acc);
      }
      const int nv = 2 * l + 1;
      #pragma unroll
      for (int reg = 0; reg < 4; ++reg) {
        int il = lk * 4 + reg;
        if (il < nv) {
          int ig = l * l + il, o = wv * 16 + lr;
          outp[(ig << 7) + o] = acc[reg] + (ig == 0 ? b2[o] : 0.f);
        }
      }
    }
  }
}

extern "C" void kernel_launch(void* const* d_in, const int* in_sizes, int n_in,
                              void* d_out, int out_size, void* d_ws, size_t ws_size,
                              hipStream_t stream) {
  const float* nf  = (const float*)d_in[0];
  const float* w1  = (const float*)d_in[1];
  const float* b1  = (const float*)d_in[2];
  const float* w2  = (const float*)d_in[3];
  const float* b2  = (const float*)d_in[4];
  const float* wsg = (const float*)d_in[5];
  const float* bs  = (const float*)d_in[6];
  const float* g1  = (const float*)d_in[7];
  const float* g2  = (const float*)d_in[8];
  const float* g3  = (const float*)d_in[9];
  const float* tg  = (const float*)d_in[10];
  const float* fg  = (const float*)d_in[11];
  ushort* wbf = (ushort*)d_ws;
  float* out = (float*)d_out;

  prep_kernel<<<(WS_TOTAL + 255) / 256, 256, 0, stream>>>(w1, w2, g1, g2, g3, tg, fg, wbf);
  ffn_main<<<1024, 512, 0, stream>>>(nf, b1, b2, wsg, bs, wbf, out);
}

// Round 8
// 555.903 us; speedup vs baseline: 1.5750x; 1.1367x over previous
//
#include <hip/hip_runtime.h>
#include <hip/hip_bf16.h>

typedef __attribute__((ext_vector_type(8))) short bf16x8;
typedef __attribute__((ext_vector_type(4))) float f32x4;

#define MFMA(a,b,c) __builtin_amdgcn_mfma_f32_16x16x32_bf16((a),(b),(c),0,0,0)

// ---- workspace (bf16) element offsets ----
#define WS_W1T 0
#define WS_W2T 229376
#define WS_G1T 458752
#define WS_TGP 655360
#define WS_FGT 679936
#define WS_TOTAL 704512

__device__ __forceinline__ ushort f2b(float f) {
  __hip_bfloat16 h = __float2bfloat16(f);
  ushort u; __builtin_memcpy(&u, &h, 2); return u;
}
__device__ __forceinline__ float silu_f(float x) { return x / (1.f + __expf(-x)); }
__device__ __forceinline__ bf16x8 ld8(const ushort* p) {
  return *reinterpret_cast<const bf16x8*>(p);
}
__device__ __forceinline__ ushort4 pk4(float a, float b, float c, float d) {
  return make_ushort4(f2b(a), f2b(b), f2b(c), f2b(d));
}

__global__ void prep_kernel(const float* __restrict__ w1, const float* __restrict__ w2,
                            const float* __restrict__ g1, const float* __restrict__ g2,
                            const float* __restrict__ g3, const float* __restrict__ tg,
                            const float* __restrict__ fg, ushort* __restrict__ o) {
  int idx = blockIdx.x * blockDim.x + threadIdx.x;
  if (idx >= WS_TOTAL) return;
  float v;
  if (idx < WS_W2T) {                        // w1T[l][h][c] = w1[l][c][h]
    int l = idx >> 15, rem = idx & 32767, h = rem >> 7, c = rem & 127;
    v = w1[(l << 15) + c * 256 + h];
  } else if (idx < WS_G1T) {                 // w2T[l][o][h] = w2[l][h][o]
    int j = idx - WS_W2T;
    int l = j >> 15, rem = j & 32767, oo = rem >> 8, h = rem & 255;
    v = w2[(l << 15) + h * 128 + oo];
  } else if (idx < WS_TGP) {                 // gT[n][k] = g[k][n]
    int j = idx - WS_G1T;
    int m = j >> 16, r = j & 65535, n2 = r >> 8, k = r & 255;
    const float* g = (m == 0) ? g1 : ((m == 1) ? g2 : g3);
    v = g[k * 256 + n2];
  } else if (idx < WS_FGT) {                 // tgP[r][i]
    int j = idx - WS_TGP, r = j >> 6, i2 = j & 63;
    v = (r < 324 && i2 < 49) ? tg[r * 49 + i2] : 0.f;
  } else {                                   // fgT[i][r]
    int j = idx - WS_FGT, i2 = j / 384, r = j % 384;
    v = (i2 < 49 && r < 324) ? fg[r * 49 + i2] : 0.f;
  }
  o[idx] = f2b(v);
}

// One block per node. 8 waves N-split (wave wv owns 32 cols). M=128 grid rows
// per outer iteration (3 iters): 2x phase size, half the barriers vs M=64.
// MFMA operand order chosen per-phase so outputs are row-contiguous -> ushort4
// LDS writes / float4 global stores (first operand's index -> reg-dim).
__global__ __launch_bounds__(512, 1) void ffn_main(
    const float* __restrict__ nf, const float* __restrict__ b1,
    const float* __restrict__ b2, const float* __restrict__ wsg,
    const float* __restrict__ bs, const ushort* __restrict__ wbf,
    float* __restrict__ out)
{
  // 138,240 B LDS -> 1 block/CU (was already 1 block/CU at 71KB due to regs)
  __shared__ __align__(16) ushort sm[69120];
  ushort* s_G   = sm;                                   // [128][264] grid rows
  ushort* s_GT  = sm + 33792;                           // [256][136] G3^T
  ushort* s_xbT = sm + 33792;                           // [256][72] x^T (alias, pre-loop)
  float*  s_gat = reinterpret_cast<float*>(sm + 68608); // [256]
  ushort* s_nf  = s_G;                                  // [52][136] prologue alias
  ushort* s_xo  = s_G;                                  // [64][264] epilogue alias

  const int tid  = threadIdx.x;
  const int lane = tid & 63;
  const int wv   = tid >> 6;    // 0..7 (N slice)
  const int lr   = lane & 15;
  const int lk   = lane >> 4;   // 0..3

  const float* nfp = nf + (size_t)blockIdx.x * 6272;

  // ---------------- prologue: zero x^T area, stage node_feats (bf16), gating ----------------
  {
    uint4 z = {0,0,0,0};
    for (int idx = tid; idx < 2304; idx += 512)         // 18432 ushorts
      *reinterpret_cast<uint4*>(&s_xbT[idx * 8]) = z;
    for (int idx = tid; idx < 52 * 32; idx += 512) {
      int r = idx >> 5, c4 = (idx & 31) << 2;
      float4 v = (r < 49) ? *reinterpret_cast<const float4*>(nfp + (r << 7) + c4)
                          : make_float4(0.f, 0.f, 0.f, 0.f);
      *reinterpret_cast<ushort4*>(&s_nf[r * 136 + c4]) = pk4(v.x, v.y, v.z, v.w);
    }
    if (tid < 256) {
      float a = bs[tid];
      #pragma unroll 4
      for (int c = 0; c < 128; ++c) a = fmaf(nfp[c], wsg[(c << 8) + tid], a);
      s_gat[tid] = silu_f(a);
    }
  }
  __syncthreads();

  // ---------------- SO3 linear 1: x^T[h][i] into s_xbT ----------------
  {
    const ushort* w1T = wbf + WS_W1T;
    #pragma unroll 1
    for (int l = 0; l < 7; ++l) {
      f32x4 a0 = {0.f,0.f,0.f,0.f}, a1 = {0.f,0.f,0.f,0.f};
      const int arow = l * l + lr;                    // <= 51, rows 49..51 zeroed
      const ushort* bb = w1T + (l << 15);
      #pragma unroll
      for (int ks = 0; ks < 4; ++ks) {
        bf16x8 af  = ld8(&s_nf[arow * 136 + ks * 32 + lk * 8]);
        bf16x8 bf0 = ld8(bb + ((wv * 32 + lr) << 7) + ks * 32 + lk * 8);
        bf16x8 bf1 = ld8(bb + ((wv * 32 + 16 + lr) << 7) + ks * 32 + lk * 8);
        a0 = MFMA(af, bf0, a0);
        a1 = MFMA(af, bf1, a1);
      }
      const int nv = 2 * l + 1;
      #pragma unroll
      for (int reg = 0; reg < 4; ++reg) {
        int il = lk * 4 + reg;
        if (il < nv) {
          int ig = l * l + il;
          int h0 = wv * 32 + lr, h1 = h0 + 16;
          s_xbT[h0 * 72 + ig] = f2b(a0[reg] + (ig == 0 ? b1[h0] : 0.f));
          s_xbT[h1 * 72 + ig] = f2b(a1[reg] + (ig == 0 ? b1[h1] : 0.f));
        }
      }
    }
  }
  __syncthreads();

  // to_grid B: x^T col-slice, persistent (16 VGPRs). s_xbT is overwritten later.
  bf16x8 xbf[2][2];
  #pragma unroll
  for (int nt = 0; nt < 2; ++nt)
    #pragma unroll
    for (int ks = 0; ks < 2; ++ks)
      xbf[nt][ks] = ld8(&s_xbT[(wv * 32 + nt * 16 + lr) * 72 + ks * 32 + lk * 8]);

  f32x4 xo[4][2];
  #pragma unroll
  for (int mt = 0; mt < 4; ++mt)
    #pragma unroll
    for (int nt = 0; nt < 2; ++nt) xo[mt][nt] = (f32x4){0.f,0.f,0.f,0.f};

  const ushort* tgP = wbf + WS_TGP;
  const ushort* fgT = wbf + WS_FGT;

  #pragma unroll 1
  for (int ch = 0; ch < 3; ++ch) {           // 128 grid rows per iteration
    // ---- TG: G = tg[128,64p] @ x[64p,256]. Swapped: reg-dim -> h. ----
    {
      f32x4 c[8][2];
      #pragma unroll
      for (int mt = 0; mt < 8; ++mt)
        #pragma unroll
        for (int nt = 0; nt < 2; ++nt) c[mt][nt] = (f32x4){0.f,0.f,0.f,0.f};
      #pragma unroll
      for (int ks = 0; ks < 2; ++ks) {
        bf16x8 atg[8];
        #pragma unroll
        for (int mt = 0; mt < 8; ++mt)
          atg[mt] = ld8(tgP + ((ch * 128 + mt * 16 + lr) << 6) + ks * 32 + lk * 8);
        #pragma unroll
        for (int mt = 0; mt < 8; ++mt)
          #pragma unroll
          for (int nt = 0; nt < 2; ++nt) c[mt][nt] = MFMA(xbf[nt][ks], atg[mt], c[mt][nt]);
      }
      #pragma unroll
      for (int mt = 0; mt < 8; ++mt)
        #pragma unroll
        for (int nt = 0; nt < 2; ++nt)
          *reinterpret_cast<ushort4*>(&s_G[(mt * 16 + lr) * 264 + wv * 32 + nt * 16 + lk * 4]) =
              pk4(c[mt][nt][0], c[mt][nt][1], c[mt][nt][2], c[mt][nt][3]);
    }
    __syncthreads();

    // ---- G-MLP passes 0,1: silu(G @ g). Swapped: reg-dim -> h -> ushort4 writes. ----
    #pragma unroll 1
    for (int pass = 0; pass < 2; ++pass) {
      const ushort* gT = wbf + WS_G1T + (pass << 16);
      f32x4 c[8][2];
      #pragma unroll
      for (int mt = 0; mt < 8; ++mt)
        #pragma unroll
        for (int nt = 0; nt < 2; ++nt) c[mt][nt] = (f32x4){0.f,0.f,0.f,0.f};
      #pragma unroll
      for (int ks = 0; ks < 8; ++ks) {
        bf16x8 bstr[2];
        #pragma unroll
        for (int nt = 0; nt < 2; ++nt)
          bstr[nt] = ld8(gT + ((wv * 32 + nt * 16 + lr) << 8) + ks * 32 + lk * 8);
        bf16x8 af[8];
        #pragma unroll
        for (int mt = 0; mt < 8; ++mt)
          af[mt] = ld8(&s_G[(mt * 16 + lr) * 264 + ks * 32 + lk * 8]);
        #pragma unroll
        for (int mt = 0; mt < 8; ++mt)
          #pragma unroll
          for (int nt = 0; nt < 2; ++nt) c[mt][nt] = MFMA(bstr[nt], af[mt], c[mt][nt]);
      }
      __syncthreads();   // all reads of s_G done before in-place overwrite
      #pragma unroll
      for (int mt = 0; mt < 8; ++mt)
        #pragma unroll
        for (int nt = 0; nt < 2; ++nt)
          *reinterpret_cast<ushort4*>(&s_G[(mt * 16 + lr) * 264 + wv * 32 + nt * 16 + lk * 4]) =
              pk4(silu_f(c[mt][nt][0]), silu_f(c[mt][nt][1]),
                  silu_f(c[mt][nt][2]), silu_f(c[mt][nt][3]));
      __syncthreads();
    }

    // ---- G3: G @ g3. Unswapped: reg-dim -> r -> ushort4 transposed write to s_GT. ----
    {
      const ushort* g3T = wbf + WS_G1T + 131072;
      f32x4 c[8][2];
      #pragma unroll
      for (int mt = 0; mt < 8; ++mt)
        #pragma unroll
        for (int nt = 0; nt < 2; ++nt) c[mt][nt] = (f32x4){0.f,0.f,0.f,0.f};
      #pragma unroll
      for (int ks = 0; ks < 8; ++ks) {
        bf16x8 bstr[2];
        #pragma unroll
        for (int nt = 0; nt < 2; ++nt)
          bstr[nt] = ld8(g3T + ((wv * 32 + nt * 16 + lr) << 8) + ks * 32 + lk * 8);
        bf16x8 af[8];
        #pragma unroll
        for (int mt = 0; mt < 8; ++mt)
          af[mt] = ld8(&s_G[(mt * 16 + lr) * 264 + ks * 32 + lk * 8]);
        #pragma unroll
        for (int mt = 0; mt < 8; ++mt)
          #pragma unroll
          for (int nt = 0; nt < 2; ++nt) c[mt][nt] = MFMA(af[mt], bstr[nt], c[mt][nt]);
      }
      __syncthreads();   // s_G reads done (next TG overwrites s_G)
      #pragma unroll
      for (int mt = 0; mt < 8; ++mt)
        #pragma unroll
        for (int nt = 0; nt < 2; ++nt) {
          int h = wv * 32 + nt * 16 + lr;
          *reinterpret_cast<ushort4*>(&s_GT[h * 136 + mt * 16 + lk * 4]) =
              pk4(c[mt][nt][0], c[mt][nt][1], c[mt][nt][2], c[mt][nt][3]);
        }
    }
    __syncthreads();

    // ---- FG: xo += fg[128]^T @ G3. Swapped: reg-dim -> h. No trailing barrier. ----
    {
      #pragma unroll
      for (int ks = 0; ks < 4; ++ks) {
        bf16x8 afg[4];
        #pragma unroll
        for (int mt = 0; mt < 4; ++mt)
          afg[mt] = ld8(fgT + (mt * 16 + lr) * 384 + ch * 128 + ks * 32 + lk * 8);
        bf16x8 bfr[2];
        #pragma unroll
        for (int nt = 0; nt < 2; ++nt)
          bfr[nt] = ld8(&s_GT[(wv * 32 + nt * 16 + lr) * 136 + ks * 32 + lk * 8]);
        #pragma unroll
        for (int mt = 0; mt < 4; ++mt)
          #pragma unroll
          for (int nt = 0; nt < 2; ++nt) xo[mt][nt] = MFMA(bfr[nt], afg[mt], xo[mt][nt]);
      }
    }
    // FG s_GT reads vs next G3 s_GT writes: >=5 barriers apart. G3 s_G reads vs
    // next TG s_G writes: 2 barriers apart.
  }

  // ---------------- epilogue: xo -> LDS (row-contig), gating row, SO3 linear 2 ----------------
  #pragma unroll
  for (int mt = 0; mt < 4; ++mt)
    #pragma unroll
    for (int nt = 0; nt < 2; ++nt)
      *reinterpret_cast<ushort4*>(&s_xo[(mt * 16 + lr) * 264 + wv * 32 + nt * 16 + lk * 4]) =
          pk4(xo[mt][nt][0], xo[mt][nt][1], xo[mt][nt][2], xo[mt][nt][3]);
  __syncthreads();
  if (tid < 256) s_xo[tid] = f2b(s_gat[tid]);   // replace row 0 with gating
  __syncthreads();

  {
    const ushort* w2T = wbf + WS_W2T;
    float* outp = out + (size_t)blockIdx.x * 6272;
    const float4 bb2 = *reinterpret_cast<const float4*>(b2 + wv * 16 + lk * 4);
    #pragma unroll 1
    for (int l = 0; l < 7; ++l) {
      f32x4 acc = {0.f,0.f,0.f,0.f};
      const ushort* bb = w2T + (l << 15);
      const int arow = l * l + lr;                 // <= 51; rows 49..63 are zeros
      #pragma unroll
      for (int ks = 0; ks < 8; ++ks) {
        bf16x8 xf = ld8(&s_xo[arow * 264 + ks * 32 + lk * 8]);
        bf16x8 wf = ld8(bb + ((wv * 16 + lr) << 8) + ks * 32 + lk * 8);
        acc = MFMA(wf, xf, acc);                   // swapped: reg-dim -> o
      }
      if (lr < 2 * l + 1) {
        int ig = l * l + lr;
        float4 v = make_float4(acc[0], acc[1], acc[2], acc[3]);
        if (ig == 0) { v.x += bb2.x; v.y += bb2.y; v.z += bb2.z; v.w += bb2.w; }
        *reinterpret_cast<float4*>(outp + (ig << 7) + wv * 16 + lk * 4) = v;
      }
    }
  }
}

extern "C" void kernel_launch(void* const* d_in, const int* in_sizes, int n_in,
                              void* d_out, int out_size, void* d_ws, size_t ws_size,
                              hipStream_t stream) {
  const float* nf  = (const float*)d_in[0];
  const float* w1  = (const float*)d_in[1];
  const float* b1  = (const float*)d_in[2];
  const float* w2  = (const float*)d_in[3];
  const float* b2  = (const float*)d_in[4];
  const float* wsg = (const float*)d_in[5];
  const float* bs  = (const float*)d_in[6];
  const float* g1  = (const float*)d_in[7];
  const float* g2  = (const float*)d_in[8];
  const float* g3  = (const float*)d_in[9];
  const float* tg  = (const float*)d_in[10];
  const float* fg  = (const float*)d_in[11];
  ushort* wbf = (ushort*)d_ws;
  float* out = (float*)d_out;

  prep_kernel<<<(WS_TOTAL + 255) / 256, 256, 0, stream>>>(w1, w2, g1, g2, g3, tg, fg, wbf);
  ffn_main<<<1024, 512, 0, stream>>>(nf, b1, b2, wsg, bs, wbf, out);
}